// Round 6
// baseline (147.831 us; speedup 1.0000x reference)
//
#include <hip/hip_runtime.h>

#define NFEAT 128
#define CAP 32        // per-destination bucket capacity (max deg ~24 for Pois(6.4) over 50k rows)
#define OVF_CAP 4096  // overflow edge list capacity (expected use: 0; correctness net)

typedef float nfloat4 __attribute__((ext_vector_type(4)));  // native vec for nontemporal builtins

// ws layout (ints): cnt[B] | ovf_cnt[1] | ovf[2*OVF_CAP] | bucket[B*CAP]

__global__ void zero_kernel(int* __restrict__ p, int n) {
    int t = blockIdx.x * blockDim.x + threadIdx.x;
    if (t < n) p[t] = 0;
}

// One pass over edges, 4 edges/thread (int4 loads): claim a slot in dst's
// bucket, store src id. Overflow (pos>=CAP) goes to a small side list.
__global__ void bin_kernel(const int* __restrict__ src, const int* __restrict__ dst,
                           int* __restrict__ cnt, int* __restrict__ ovf_cnt,
                           int* __restrict__ ovf, int* __restrict__ bucket,
                           int E, int B) {
    int t = blockIdx.x * blockDim.x + threadIdx.x;
    int e0 = t << 2;
    if (e0 >= E) return;
    int s[4], d[4];
    int m;
    if (e0 + 4 <= E) {
        m = 4;
        int4 sv = *(const int4*)(src + e0);
        int4 dv = *(const int4*)(dst + e0);
        s[0] = sv.x; s[1] = sv.y; s[2] = sv.z; s[3] = sv.w;
        d[0] = dv.x; d[1] = dv.y; d[2] = dv.z; d[3] = dv.w;
    } else {
        m = E - e0;
        for (int i = 0; i < m; ++i) { s[i] = src[e0 + i]; d[i] = dst[e0 + i]; }
    }
    #pragma unroll
    for (int i = 0; i < 4; ++i) {
        if (i >= m) break;
        int dd = d[i];
        if (dd >= B) continue;
        int pos = atomicAdd(&cnt[dd], 1);
        if (pos < CAP) {
            bucket[dd * CAP + pos] = s[i];
        } else {
            int o = atomicAdd(ovf_cnt, 1);
            if (o < OVF_CAP) { ovf[2 * o] = s[i]; ovf[2 * o + 1] = dd; }
        }
    }
}

__global__ void bin_kernel_scalar(const int* __restrict__ src, const int* __restrict__ dst,
                                  int* __restrict__ cnt, int* __restrict__ ovf_cnt,
                                  int* __restrict__ ovf, int* __restrict__ bucket,
                                  int E, int B) {
    int e = blockIdx.x * blockDim.x + threadIdx.x;
    if (e >= E) return;
    int dd = dst[e];
    if (dd >= B) return;
    int pos = atomicAdd(&cnt[dd], 1);
    if (pos < CAP) bucket[dd * CAP + pos] = src[e];
    else { int o = atomicAdd(ovf_cnt, 1); if (o < OVF_CAP) { ovf[2 * o] = src[e]; ovf[2 * o + 1] = dd; } }
}

// Two destination rows per wave: half-wave (32 lanes) per row, float4/lane.
// Branchless, tail-free gather loop: km = max(k0,k1) (wave-uniform), step 8,
// masked slots clamp to last valid id (cache-hit reload) and FMA by 0.
// => 8 independent 512B row-gathers in flight per half-row, zero divergence.
__global__ __launch_bounds__(256, 8)
void aggregate_kernel(const float4* __restrict__ x4,
                      const int* __restrict__ cnt,
                      const int* __restrict__ bucket,
                      const int* __restrict__ ovf_cnt,
                      const int* __restrict__ ovf,
                      float4* __restrict__ out4, int B) {
    int wid = (blockIdx.x * blockDim.x + threadIdx.x) >> 6;
    int lane = threadIdx.x & 63;
    int half = lane >> 5;          // which of the wave's 2 rows
    int c = lane & 31;             // float4 chunk within the feature row
    int bl = half << 5;
    int w = (wid << 1) + half;
    bool rv = (w < B);
    int wv = rv ? w : 0;
    int k = cnt[wv];
    if (k > CAP) k = CAP;
    if (!rv) k = 0;
    int ko = __shfl(k, lane ^ 32, 64);
    int km = (k > ko) ? k : ko;                    // wave-uniform loop bound
    int sid = (c < k) ? bucket[wv * CAP + c] : 0;  // coalesced id preload
    float4 xd = x4[(size_t)wv * 32 + c];           // left-half copy, issue early
    float4 acc = make_float4(0.f, 0.f, 0.f, 0.f);
    int kc = (k > 0) ? (k - 1) : 0;                // clamp target for masked slots
    for (int j = 0; j < km; j += 8) {
        int   idx[8];
        float msk[8];
        #pragma unroll
        for (int i = 0; i < 8; ++i) {
            int jj = j + i;
            int jc = (jj < kc) ? jj : kc;          // safe slot (re-reads last valid row)
            idx[i] = __shfl(sid, bl + jc, 64);
            msk[i] = (jj < k) ? 1.f : 0.f;
        }
        float4 v[8];
        #pragma unroll
        for (int i = 0; i < 8; ++i) v[i] = x4[(size_t)idx[i] * 32 + c];
        #pragma unroll
        for (int i = 0; i < 8; ++i) {
            acc.x = fmaf(msk[i], v[i].x, acc.x);
            acc.y = fmaf(msk[i], v[i].y, acc.y);
            acc.z = fmaf(msk[i], v[i].z, acc.z);
            acc.w = fmaf(msk[i], v[i].w, acc.w);
        }
    }
    // overflow edges (expected n == 0): exact correctness net
    int n = *ovf_cnt;
    if (n > OVF_CAP) n = OVF_CAP;
    for (int i = 0; i < n; ++i) {
        if (rv && ovf[2 * i + 1] == w) {
            float4 v = x4[(size_t)ovf[2 * i] * 32 + c];
            acc.x += v.x; acc.y += v.y; acc.z += v.z; acc.w += v.w;
        }
    }
    if (rv) {
        size_t o = (size_t)w * 64;
        nfloat4 xv = { xd.x, xd.y, xd.z, xd.w };
        nfloat4 av = { acc.x, acc.y, acc.z, acc.w };
        __builtin_nontemporal_store(xv, (nfloat4*)&out4[o + c]);        // cols 0..127
        __builtin_nontemporal_store(av, (nfloat4*)&out4[o + 32 + c]);   // cols 128..255
    }
}

// ---------------- Fallback (no-ws): R0 atomic path ----------------
__global__ void init_out_kernel(const float4* __restrict__ x4,
                                float4* __restrict__ out4, int B) {
    int t = blockIdx.x * blockDim.x + threadIdx.x;
    if (t >= B * 64) return;
    int row = t >> 6, c = t & 63;
    float4 v = (c < 32) ? x4[(size_t)row * 32 + c] : make_float4(0.f, 0.f, 0.f, 0.f);
    out4[t] = v;
}

__global__ void edge_scatter_atomic_kernel(const float* __restrict__ x,
                                           const int* __restrict__ src,
                                           const int* __restrict__ dst,
                                           float* __restrict__ out, int E, int B) {
    int t = blockIdx.x * blockDim.x + threadIdx.x;
    int e = t >> 5;
    if (e >= E) return;
    int d = dst[e];
    if (d >= B) return;
    int c = t & 31;
    const float4 v = ((const float4*)(x + (size_t)src[e] * NFEAT))[c];
    float* o = out + (size_t)d * 256 + NFEAT + c * 4;
    unsafeAtomicAdd(o + 0, v.x);
    unsafeAtomicAdd(o + 1, v.y);
    unsafeAtomicAdd(o + 2, v.z);
    unsafeAtomicAdd(o + 3, v.w);
}

extern "C" void kernel_launch(void* const* d_in, const int* in_sizes, int n_in,
                              void* d_out, int out_size, void* d_ws, size_t ws_size,
                              hipStream_t stream) {
    const float* x  = (const float*)d_in[0];
    const int*   ei = (const int*)d_in[1];
    const int E = in_sizes[1] / 2;
    const int B = out_size / (2 * NFEAT);
    float* out = (float*)d_out;
    const int* src = ei;
    const int* dst = ei + E;

    size_t need = ((size_t)B * (CAP + 1) + 1 + 2 * OVF_CAP) * sizeof(int);
    if (ws_size >= need) {
        int* cnt     = (int*)d_ws;
        int* ovf_cnt = cnt + B;
        int* ovf     = ovf_cnt + 1;
        int* bucket  = ovf + 2 * OVF_CAP;

        int nz = B + 1;
        zero_kernel<<<(nz + 255) / 256, 256, 0, stream>>>(cnt, nz);
        if ((E & 3) == 0) {
            int nt = E / 4;
            bin_kernel<<<(nt + 255) / 256, 256, 0, stream>>>(
                src, dst, cnt, ovf_cnt, ovf, bucket, E, B);
        } else {
            bin_kernel_scalar<<<(E + 255) / 256, 256, 0, stream>>>(
                src, dst, cnt, ovf_cnt, ovf, bucket, E, B);
        }
        int waves = (B + 1) / 2;
        aggregate_kernel<<<(waves + 3) / 4, 256, 0, stream>>>(
            (const float4*)x, cnt, bucket, ovf_cnt, ovf, (float4*)out, B);
    } else {
        init_out_kernel<<<(B * 64 + 255) / 256, 256, 0, stream>>>(
            (const float4*)x, (float4*)out, B);
        long long total = (long long)E * 32;
        edge_scatter_atomic_kernel<<<(int)((total + 255) / 256), 256, 0, stream>>>(
            x, src, dst, out, E, B);
    }
}

// Round 7
// 141.242 us; speedup vs baseline: 1.0466x; 1.0466x over previous
//
#include <hip/hip_runtime.h>

#define NFEAT 128
#define CAP 32        // per-destination bucket capacity (max deg ~24 for Pois(6.4) over 50k rows)
#define OVF_CAP 4096  // overflow edge list capacity (expected use: 0; correctness net)

// ws layout (ints): cnt[B] | ovf_cnt[1] | ovf[2*OVF_CAP] | bucket[B*CAP]

__global__ void zero_kernel(int* __restrict__ p, int n) {
    int t = blockIdx.x * blockDim.x + threadIdx.x;
    if (t < n) p[t] = 0;
}

// One pass over edges, 4 edges/thread (int4 loads): claim a slot in dst's
// bucket, store src id. Overflow (pos>=CAP) goes to a small side list.
// Also fuses the out[:,0:128] = x[:B] streaming copy: bin is atomic-latency
// bound, so the copy rides the idle BW pipe (and shrinks aggregate's writes).
__global__ void bin_kernel(const int* __restrict__ src, const int* __restrict__ dst,
                           int* __restrict__ cnt, int* __restrict__ ovf_cnt,
                           int* __restrict__ ovf, int* __restrict__ bucket,
                           const float4* __restrict__ x4, float4* __restrict__ out4,
                           int E, int B, int nthreads) {
    int t = blockIdx.x * blockDim.x + threadIdx.x;
    int e0 = t << 2;
    int s[4], d[4];
    int m = 0;
    if (e0 < E) {
        if (e0 + 4 <= E) {
            m = 4;
            int4 sv = *(const int4*)(src + e0);
            int4 dv = *(const int4*)(dst + e0);
            s[0] = sv.x; s[1] = sv.y; s[2] = sv.z; s[3] = sv.w;
            d[0] = dv.x; d[1] = dv.y; d[2] = dv.z; d[3] = dv.w;
        } else {
            m = E - e0;
            for (int i = 0; i < m; ++i) { s[i] = src[e0 + i]; d[i] = dst[e0 + i]; }
        }
    }
    // Streaming copy of left output halves while the edge loads are in flight.
    int total4 = B * 32;               // one float4 per (row, chunk) of left half
    for (int i = t; i < total4; i += nthreads) {
        int row = i >> 5, c = i & 31;
        out4[(size_t)row * 64 + c] = x4[(size_t)row * 32 + c];
    }
    #pragma unroll
    for (int i = 0; i < 4; ++i) {
        if (i >= m) break;
        int dd = d[i];
        if (dd >= B) continue;
        int pos = atomicAdd(&cnt[dd], 1);
        if (pos < CAP) {
            bucket[dd * CAP + pos] = s[i];
        } else {
            int o = atomicAdd(ovf_cnt, 1);
            if (o < OVF_CAP) { ovf[2 * o] = s[i]; ovf[2 * o + 1] = dd; }
        }
    }
}

// Two destination rows per wave: half-wave (32 lanes) per row, float4/lane.
// Branchless, tail-free gather loop: km = max(k0,k1) (wave-uniform), step 8,
// masked slots clamp to last valid id (L1-hit reload) and FMA by 0.
// Writes ONLY the right output half (left half written by bin_kernel).
__global__ void aggregate_kernel(const float4* __restrict__ x4,
                                 const int* __restrict__ cnt,
                                 const int* __restrict__ bucket,
                                 const int* __restrict__ ovf_cnt,
                                 const int* __restrict__ ovf,
                                 float4* __restrict__ out4, int B) {
    int wid = (blockIdx.x * blockDim.x + threadIdx.x) >> 6;
    int lane = threadIdx.x & 63;
    int half = lane >> 5;          // which of the wave's 2 rows
    int c = lane & 31;             // float4 chunk within the feature row
    int bl = half << 5;
    int w = (wid << 1) + half;
    bool rv = (w < B);
    int wv = rv ? w : 0;
    int k = cnt[wv];
    if (k > CAP) k = CAP;
    if (!rv) k = 0;
    int ko = __shfl(k, lane ^ 32, 64);
    int km = (k > ko) ? k : ko;                    // wave-uniform loop bound
    int sid = (c < k) ? bucket[wv * CAP + c] : 0;  // coalesced id preload
    float4 acc = make_float4(0.f, 0.f, 0.f, 0.f);
    int kc = (k > 0) ? (k - 1) : 0;                // clamp target for masked slots
    for (int j = 0; j < km; j += 8) {
        int   idx[8];
        float msk[8];
        #pragma unroll
        for (int i = 0; i < 8; ++i) {
            int jj = j + i;
            int jc = (jj < kc) ? jj : kc;          // safe slot (L1-hit re-read)
            idx[i] = __shfl(sid, bl + jc, 64);
            msk[i] = (jj < k) ? 1.f : 0.f;
        }
        float4 v[8];
        #pragma unroll
        for (int i = 0; i < 8; ++i) v[i] = x4[(size_t)idx[i] * 32 + c];
        #pragma unroll
        for (int i = 0; i < 8; ++i) {
            acc.x = fmaf(msk[i], v[i].x, acc.x);
            acc.y = fmaf(msk[i], v[i].y, acc.y);
            acc.z = fmaf(msk[i], v[i].z, acc.z);
            acc.w = fmaf(msk[i], v[i].w, acc.w);
        }
    }
    // overflow edges (expected n == 0): exact correctness net
    int n = *ovf_cnt;
    if (n > OVF_CAP) n = OVF_CAP;
    for (int i = 0; i < n; ++i) {
        if (rv && ovf[2 * i + 1] == w) {
            float4 v = x4[(size_t)ovf[2 * i] * 32 + c];
            acc.x += v.x; acc.y += v.y; acc.z += v.z; acc.w += v.w;
        }
    }
    if (rv) {
        out4[(size_t)w * 64 + 32 + c] = acc;       // cols 128..255 only
    }
}

// ---------------- Fallback (no-ws): R0 atomic path ----------------
__global__ void init_out_kernel(const float4* __restrict__ x4,
                                float4* __restrict__ out4, int B) {
    int t = blockIdx.x * blockDim.x + threadIdx.x;
    if (t >= B * 64) return;
    int row = t >> 6, c = t & 63;
    float4 v = (c < 32) ? x4[(size_t)row * 32 + c] : make_float4(0.f, 0.f, 0.f, 0.f);
    out4[t] = v;
}

__global__ void edge_scatter_atomic_kernel(const float* __restrict__ x,
                                           const int* __restrict__ src,
                                           const int* __restrict__ dst,
                                           float* __restrict__ out, int E, int B) {
    int t = blockIdx.x * blockDim.x + threadIdx.x;
    int e = t >> 5;
    if (e >= E) return;
    int d = dst[e];
    if (d >= B) return;
    int c = t & 31;
    const float4 v = ((const float4*)(x + (size_t)src[e] * NFEAT))[c];
    float* o = out + (size_t)d * 256 + NFEAT + c * 4;
    unsafeAtomicAdd(o + 0, v.x);
    unsafeAtomicAdd(o + 1, v.y);
    unsafeAtomicAdd(o + 2, v.z);
    unsafeAtomicAdd(o + 3, v.w);
}

extern "C" void kernel_launch(void* const* d_in, const int* in_sizes, int n_in,
                              void* d_out, int out_size, void* d_ws, size_t ws_size,
                              hipStream_t stream) {
    const float* x  = (const float*)d_in[0];
    const int*   ei = (const int*)d_in[1];
    const int E = in_sizes[1] / 2;
    const int B = out_size / (2 * NFEAT);
    float* out = (float*)d_out;
    const int* src = ei;
    const int* dst = ei + E;

    size_t need = ((size_t)B * (CAP + 1) + 1 + 2 * OVF_CAP) * sizeof(int);
    if (ws_size >= need && (E & 3) == 0) {
        int* cnt     = (int*)d_ws;
        int* ovf_cnt = cnt + B;
        int* ovf     = ovf_cnt + 1;
        int* bucket  = ovf + 2 * OVF_CAP;

        int nz = B + 1;
        zero_kernel<<<(nz + 255) / 256, 256, 0, stream>>>(cnt, nz);
        int nt = E / 4;
        int nblocks = (nt + 255) / 256;
        bin_kernel<<<nblocks, 256, 0, stream>>>(
            src, dst, cnt, ovf_cnt, ovf, bucket,
            (const float4*)x, (float4*)out, E, B, nblocks * 256);
        int waves = (B + 1) / 2;
        aggregate_kernel<<<(waves + 3) / 4, 256, 0, stream>>>(
            (const float4*)x, cnt, bucket, ovf_cnt, ovf, (float4*)out, B);
    } else {
        init_out_kernel<<<(B * 64 + 255) / 256, 256, 0, stream>>>(
            (const float4*)x, (float4*)out, B);
        long long total = (long long)E * 32;
        edge_scatter_atomic_kernel<<<(int)((total + 255) / 256), 256, 0, stream>>>(
            x, src, dst, out, E, B);
    }
}